// Round 2
// baseline (2775.901 us; speedup 1.0000x reference)
//
#include <hip/hip_runtime.h>
#include <hip/hip_bf16.h>

// ---------------------------------------------------------------------------
// WinEncoderTransformer mega-kernel: one block per batch element (bc),
// activations resident in LDS (bf16), weights pre-transposed to bf16 in d_ws.
// Geometry: N=128, B=1024, C=256; block bc owns flat rows [bc*128, bc*128+128).
// ---------------------------------------------------------------------------

#define ATT_SCALE 0.17677669529663687f   // 32^-0.5

typedef float f32x4 __attribute__((ext_vector_type(4)));
typedef __bf16 bf16x8 __attribute__((ext_vector_type(8)));
typedef unsigned short u16x8 __attribute__((ext_vector_type(8)));
typedef unsigned short u16x4 __attribute__((ext_vector_type(4)));

__device__ __forceinline__ unsigned short f2bf(float f) {
    unsigned int u = __float_as_uint(f);
    return (unsigned short)((u + 0x7FFFu + ((u >> 16) & 1u)) >> 16);  // RNE
}
__device__ __forceinline__ float bf2f(unsigned short s) {
    return __uint_as_float(((unsigned int)s) << 16);
}

// ---------------------------------------------------------------------------
// weight prep: src [L][K][N] f32 -> dst [L][N][K] bf16 (transposed)
// ---------------------------------------------------------------------------
__global__ __launch_bounds__(256) void wprep(const float* __restrict__ src,
                                             unsigned short* __restrict__ dst,
                                             int K, int N)
{
    __shared__ unsigned short t[32][33];
    int l = blockIdx.z;
    const float* s = src + (size_t)l * K * N;
    unsigned short* d = dst + (size_t)l * K * N;
    int r = threadIdx.x >> 3, c4 = (threadIdx.x & 7) * 4;
    int kb = blockIdx.x * 32, nb = blockIdx.y * 32;
    f32x4 v = *(const f32x4*)(s + (size_t)(kb + r) * N + nb + c4);
    #pragma unroll
    for (int j = 0; j < 4; ++j) t[c4 + j][r] = f2bf(v[j]);
    __syncthreads();
    u16x4 o;
    #pragma unroll
    for (int j = 0; j < 4; ++j) o[j] = t[r][c4 + j];
    *(u16x4*)(d + (size_t)(nb + r) * K + kb + c4) = o;
}

// ---------------------------------------------------------------------------
// MFMA tile GEMM: A from swizzled LDS (bf16), B from global transposed bf16
// (BT pre-offset by wave's n0*ldbk). acc C/D layout: col=lr, row=lk*4+j.
// LDS swizzle convention everywhere: byte = (row*stride + colbyte) ^ ((row&7)<<4)
// (strides are multiples of 256 so the XOR stays inside the row).
// ---------------------------------------------------------------------------
template<int MT, int NT, int KS>
__device__ __forceinline__ void mfma_gemm(const char* As, int astride, int am0,
    const unsigned short* __restrict__ BT, int ldbk, int koff,
    int lr, int lk, f32x4 (&acc)[MT][NT])
{
    #pragma unroll
    for (int s = 0; s < KS; ++s) {
        bf16x8 bfr[NT];
        #pragma unroll
        for (int nt = 0; nt < NT; ++nt)
            bfr[nt] = *(const bf16x8*)(BT + (size_t)(nt * 16 + lr) * ldbk + koff + s * 32 + lk * 8);
        #pragma unroll
        for (int mt = 0; mt < MT; ++mt) {
            int row = am0 + mt * 16 + lr;
            bf16x8 afr = *(const bf16x8*)(As + ((row * astride + s * 64 + lk * 16) ^ ((row & 7) << 4)));
            #pragma unroll
            for (int nt = 0; nt < NT; ++nt)
                acc[mt][nt] = __builtin_amdgcn_mfma_f32_16x16x32_bf16(afr, bfr[nt], acc[mt][nt], 0, 0, 0);
        }
    }
}

template<int MT, int NT, bool RELU>
__device__ __forceinline__ void store_lds(char* Ds, int dstride, int dm0, int dn0,
    const float* bias, int lr, int lk, f32x4 (&acc)[MT][NT])
{
    #pragma unroll
    for (int nt = 0; nt < NT; ++nt) {
        float bv = bias ? bias[nt * 16 + lr] : 0.0f;
        #pragma unroll
        for (int mt = 0; mt < MT; ++mt) {
            #pragma unroll
            for (int j = 0; j < 4; ++j) {
                int row = dm0 + mt * 16 + lk * 4 + j;
                int col = dn0 + nt * 16 + lr;
                float v = acc[mt][nt][j] + bv;
                if (RELU) v = fmaxf(v, 0.0f);
                *(unsigned short*)(Ds + ((row * dstride + col * 2) ^ ((row & 7) << 4))) = f2bf(v);
            }
        }
    }
}

// read/write 32 consecutive bf16 (4 swizzled 16B chunks) as floats
__device__ __forceinline__ void lds_read32(const char* base, int stride, int row, int cb, float* o) {
    int x = row * stride, sw = (row & 7) << 4;
    #pragma unroll
    for (int c = 0; c < 4; ++c) {
        u16x8 t = *(const u16x8*)(base + ((x + cb + c * 16) ^ sw));
        #pragma unroll
        for (int j = 0; j < 8; ++j) o[c * 8 + j] = bf2f(t[j]);
    }
}
__device__ __forceinline__ void lds_write32(char* base, int stride, int row, int cb, const float* v) {
    int x = row * stride, sw = (row & 7) << 4;
    #pragma unroll
    for (int c = 0; c < 4; ++c) {
        u16x8 t;
        #pragma unroll
        for (int j = 0; j < 8; ++j) t[j] = f2bf(v[c * 8 + j]);
        *(u16x8*)(base + ((x + cb + c * 16) ^ sw)) = t;
    }
}

// ---------------------------------------------------------------------------
// LN over 256 cols. thread: row = tid>>2, quarter (tid&3)*64.
// mode 0: a = [hi(aHi,stride256) | lo(aLo,stride256)]; mode 1: a = aHi stride 512;
// mode 2: no residual. outp != null -> write f32 global, else write xs (bf16).
// ---------------------------------------------------------------------------
__device__ void ln_rows(char* xs, const char* aHi, const char* aLo, int mode,
                        const float* g, const float* b, int tid, float* outp)
{
    int row = tid >> 2, c0 = (tid & 3) * 64;
    float v[64];
    {
        int x = row * 512, sw = (row & 7) << 4;
        #pragma unroll
        for (int c = 0; c < 8; ++c) {
            u16x8 t = *(const u16x8*)(xs + ((x + c0 * 2 + c * 16) ^ sw));
            #pragma unroll
            for (int j = 0; j < 8; ++j) v[c * 8 + j] = bf2f(t[j]);
        }
    }
    if (mode == 0) {
        const char* ab = (c0 < 128) ? aHi : aLo;
        int cb = (c0 < 128) ? c0 * 2 : (c0 - 128) * 2;
        int x = row * 256, sw = (row & 7) << 4;
        #pragma unroll
        for (int c = 0; c < 8; ++c) {
            u16x8 t = *(const u16x8*)(ab + ((x + cb + c * 16) ^ sw));
            #pragma unroll
            for (int j = 0; j < 8; ++j) v[c * 8 + j] += bf2f(t[j]);
        }
    } else if (mode == 1) {
        int x = row * 512, sw = (row & 7) << 4;
        #pragma unroll
        for (int c = 0; c < 8; ++c) {
            u16x8 t = *(const u16x8*)(aHi + ((x + c0 * 2 + c * 16) ^ sw));
            #pragma unroll
            for (int j = 0; j < 8; ++j) v[c * 8 + j] += bf2f(t[j]);
        }
    }
    float s = 0.0f, sq = 0.0f;
    #pragma unroll
    for (int j = 0; j < 64; ++j) { s += v[j]; sq += v[j] * v[j]; }
    s += __shfl_xor(s, 1); s += __shfl_xor(s, 2);
    sq += __shfl_xor(sq, 1); sq += __shfl_xor(sq, 2);
    float mean = s * (1.0f / 256.0f);
    float var = sq * (1.0f / 256.0f) - mean * mean;
    float rstd = rsqrtf(var + 1e-5f);
    if (outp) {
        float* op = outp + (size_t)row * 256 + c0;
        #pragma unroll
        for (int c = 0; c < 16; ++c) {
            f32x4 gv = *(const f32x4*)(g + c0 + c * 4);
            f32x4 bv = *(const f32x4*)(b + c0 + c * 4);
            f32x4 ov;
            #pragma unroll
            for (int j = 0; j < 4; ++j) ov[j] = (v[c * 4 + j] - mean) * rstd * gv[j] + bv[j];
            *(f32x4*)(op + c * 4) = ov;
        }
    } else {
        int x = row * 512, sw = (row & 7) << 4;
        #pragma unroll
        for (int c = 0; c < 8; ++c) {
            u16x8 t;
            #pragma unroll
            for (int j = 0; j < 8; ++j) {
                float nv = (v[c * 8 + j] - mean) * rstd * g[c0 + c * 8 + j] + b[c0 + c * 8 + j];
                t[j] = f2bf(nv);
            }
            *(u16x8*)(xs + ((x + c0 * 2 + c * 16) ^ sw)) = t;
        }
    }
}

// ---------------------------------------------------------------------------
// The mega-kernel. 512 threads = 8 waves (2m x 4n for 128-row GEMMs).
// Dynamic LDS 160 KiB: xs[128][256]bf16 (64K) | sbuf 96K = R0|R1|R2 (32K each).
// ---------------------------------------------------------------------------
__global__ __launch_bounds__(512, 1) void enc_kernel(
    const float* __restrict__ tgt,
    const unsigned short* __restrict__ tWhqkv,  // [L][384][256]
    const unsigned short* __restrict__ tWhp,    // [L][128][128]
    const unsigned short* __restrict__ tWlq,    // [L][128][256]
    const unsigned short* __restrict__ tWlkv,   // [L][256][256]
    const unsigned short* __restrict__ tWlp,    // [L][128][128]
    const unsigned short* __restrict__ tW1,     // [L][512][256]
    const unsigned short* __restrict__ tW2,     // [L][256][512]
    const float* __restrict__ bhp, const float* __restrict__ blp,
    const float* __restrict__ b1, const float* __restrict__ b2,
    const float* __restrict__ ln1g, const float* __restrict__ ln1b,
    const float* __restrict__ ln2g, const float* __restrict__ ln2b,
    const float* __restrict__ lnfg, const float* __restrict__ lnfb,
    float* __restrict__ out)
{
    extern __shared__ char smem[];
    char* xs = smem;              // [128] rows x 512 B (256 bf16), swizzled
    char* sb = smem + 65536;      // 96 KB scratch
    char* R0 = sb;
    char* R1 = sb + 32768;
    char* R2 = sb + 65536;

    const int tid = threadIdx.x;
    const int bc = blockIdx.x;
    const int w = tid >> 6, l = tid & 63;
    const int lr = l & 15, lk = l >> 4;
    const int wm = w >> 2, wn = w & 3;   // 2 x 4 wave grid

    // ---- load x tile: 128 rows x 256 f32 -> bf16 swizzled LDS ----
    {
        int row = tid >> 2, c0 = (tid & 3) * 64;
        const float* src = tgt + ((size_t)bc * 128 + row) * 256 + c0;
        int x = row * 512, sw = (row & 7) << 4;
        #pragma unroll
        for (int c = 0; c < 8; ++c) {
            f32x4 a = *(const f32x4*)(src + c * 8);
            f32x4 bq = *(const f32x4*)(src + c * 8 + 4);
            u16x8 t;
            #pragma unroll
            for (int j = 0; j < 4; ++j) { t[j] = f2bf(a[j]); t[4 + j] = f2bf(bq[j]); }
            *(u16x8*)(xs + ((x + c0 * 2 + c * 16) ^ sw)) = t;
        }
    }
    __syncthreads();

    for (int li = 0; li < 2; ++li) {
        // ---- P1: qkv = xs @ WhqkvT  (128x384, K=256) -> sb rows stride 768 ----
        {
            f32x4 acc[4][6] = {};
            mfma_gemm<4, 6, 8>(xs, 512, wm * 64,
                tWhqkv + (size_t)li * 98304 + (size_t)(wn * 96) * 256, 256, 0, lr, lk, acc);
            store_lds<4, 6, false>(sb, 768, wm * 64, wn * 96, nullptr, lr, lk, acc);
        }
        __syncthreads();
        // ---- P2: hifi windowed attention (thread = win,h,qi) ----
        {
            int win = tid >> 4, h = (tid >> 2) & 3, qi = tid & 3;
            int rbase = ((win >> 3) << 5) + ((win & 7) << 1);
            int qrow = rbase + ((qi >> 1) << 4) + (qi & 1);
            float q[32], kk[32], o[32];
            lds_read32(sb, 768, qrow, h * 64, q);
            float s4[4];
            #pragma unroll
            for (int j = 0; j < 4; ++j) {
                int kr = rbase + ((j >> 1) << 4) + (j & 1);
                lds_read32(sb, 768, kr, 256 + h * 64, kk);
                float d = 0.0f;
                #pragma unroll
                for (int i = 0; i < 32; ++i) d += q[i] * kk[i];
                s4[j] = d * ATT_SCALE;
            }
            float mx = fmaxf(fmaxf(s4[0], s4[1]), fmaxf(s4[2], s4[3]));
            float den = 0.0f;
            #pragma unroll
            for (int j = 0; j < 4; ++j) { s4[j] = __expf(s4[j] - mx); den += s4[j]; }
            float inv = 1.0f / den;
            #pragma unroll
            for (int i = 0; i < 32; ++i) o[i] = 0.0f;
            #pragma unroll
            for (int j = 0; j < 4; ++j) {
                int vr = rbase + ((j >> 1) << 4) + (j & 1);
                lds_read32(sb, 768, vr, 512 + h * 64, kk);
                float a = s4[j] * inv;
                #pragma unroll
                for (int i = 0; i < 32; ++i) o[i] += a * kk[i];
            }
            __syncthreads();                       // all qkv reads done
            lds_write32(R0, 256, qrow, h * 64, o); // os -> R0
        }
        __syncthreads();
        // ---- P3: hi = os @ WhpT + bhp -> R1 (as_hi) ----
        {
            f32x4 acc[4][2] = {};
            mfma_gemm<4, 2, 4>(R0, 256, wm * 64,
                tWhp + (size_t)li * 16384 + (size_t)(wn * 32) * 128, 128, 0, lr, lk, acc);
            store_lds<4, 2, false>(R1, 256, wm * 64, wn * 32,
                bhp + li * 128 + wn * 32, lr, lk, acc);
        }
        __syncthreads();
        // ---- P4: pool 2x2 windows -> xps R2[0:16K], [32][256] stride 512 ----
        {
            int p = tid >> 4, c16 = (tid & 15) * 16;
            int rb = ((p >> 3) << 5) + ((p & 7) << 1);
            int rows[4] = {rb, rb + 1, rb + 16, rb + 17};
            float a16[16] = {};
            #pragma unroll
            for (int rr = 0; rr < 4; ++rr) {
                int r = rows[rr];
                int x = r * 512, sw = (r & 7) << 4;
                #pragma unroll
                for (int c = 0; c < 2; ++c) {
                    u16x8 t = *(const u16x8*)(xs + ((x + c16 * 2 + c * 16) ^ sw));
                    #pragma unroll
                    for (int j = 0; j < 8; ++j) a16[c * 8 + j] += bf2f(t[j]);
                }
            }
            int x = p * 512, sw = (p & 7) << 4;
            #pragma unroll
            for (int c = 0; c < 2; ++c) {
                u16x8 t;
                #pragma unroll
                for (int j = 0; j < 8; ++j) t[j] = f2bf(a16[c * 8 + j] * 0.25f);
                *(u16x8*)(R2 + ((x + c16 * 2 + c * 16) ^ sw)) = t;
            }
        }
        __syncthreads();
        // ---- P5: kv = xps @ WlkvT (32x256) -> kvs R2+16K; P6: q = xs @ WlqT -> R0 ----
        {
            f32x4 acc[2][2] = {};
            mfma_gemm<2, 2, 8>(R2, 512, 0,
                tWlkv + (size_t)li * 65536 + (size_t)(w * 32) * 256, 256, 0, lr, lk, acc);
            store_lds<2, 2, false>(R2 + 16384, 512, 0, w * 32, nullptr, lr, lk, acc);
        }
        {
            f32x4 acc[4][2] = {};
            mfma_gemm<4, 2, 8>(xs, 512, wm * 64,
                tWlq + (size_t)li * 32768 + (size_t)(wn * 32) * 256, 256, 0, lr, lk, acc);
            store_lds<4, 2, false>(R0, 256, wm * 64, wn * 32, nullptr, lr, lk, acc);
        }
        __syncthreads();
        // ---- P7: lofi attention (thread = row,h): q(R0) vs kvs(R2+16K) ----
        {
            int row = tid >> 2, h = tid & 3;
            float q[32], kk[32], o[32], sc[32];
            lds_read32(R0, 256, row, h * 64, q);
            #pragma unroll
            for (int p = 0; p < 32; ++p) {
                lds_read32(R2 + 16384, 512, p, h * 64, kk);
                float d = 0.0f;
                #pragma unroll
                for (int i = 0; i < 32; ++i) d += q[i] * kk[i];
                sc[p] = d * ATT_SCALE;
            }
            float mx = -1e30f;
            #pragma unroll
            for (int p = 0; p < 32; ++p) mx = fmaxf(mx, sc[p]);
            float den = 0.0f;
            #pragma unroll
            for (int p = 0; p < 32; ++p) { sc[p] = __expf(sc[p] - mx); den += sc[p]; }
            float inv = 1.0f / den;
            #pragma unroll
            for (int i = 0; i < 32; ++i) o[i] = 0.0f;
            #pragma unroll
            for (int p = 0; p < 32; ++p) {
                lds_read32(R2 + 16384, 512, p, 256 + h * 64, kk);
                float a = sc[p];
                #pragma unroll
                for (int i = 0; i < 32; ++i) o[i] += a * kk[i];
            }
            #pragma unroll
            for (int i = 0; i < 32; ++i) o[i] *= inv;
            __syncthreads();                        // all q/kv reads done
            lds_write32(R2, 256, row, h * 64, o);   // los -> R2
        }
        __syncthreads();
        // ---- P8: lo = los @ WlpT + blp -> R0 (as_lo) ----
        {
            f32x4 acc[4][2] = {};
            mfma_gemm<4, 2, 4>(R2, 256, wm * 64,
                tWlp + (size_t)li * 16384 + (size_t)(wn * 32) * 128, 128, 0, lr, lk, acc);
            store_lds<4, 2, false>(R0, 256, wm * 64, wn * 32,
                blp + li * 128 + wn * 32, lr, lk, acc);
        }
        __syncthreads();
        // ---- P9: x = LN(x + [hi|lo]) ----
        ln_rows(xs, R1, R0, 0, ln1g + li * 256, ln1b + li * 256, tid, nullptr);
        __syncthreads();
        // ---- P10/P11: FFN with K-split, f accumulated in registers ----
        {
            f32x4 facc[4][4] = {};
            #pragma unroll
            for (int h = 0; h < 2; ++h) {
                f32x4 acch[4][4] = {};
                mfma_gemm<4, 4, 8>(xs, 512, wm * 64,
                    tW1 + (size_t)li * 131072 + (size_t)(h * 256 + wn * 64) * 256, 256, 0, lr, lk, acch);
                store_lds<4, 4, true>(R0, 512, wm * 64, wn * 64,
                    b1 + li * 512 + h * 256 + wn * 64, lr, lk, acch);
                __syncthreads();
                mfma_gemm<4, 4, 8>(R0, 512, wm * 64,
                    tW2 + (size_t)li * 131072 + (size_t)(wn * 64) * 512, 512, h * 256, lr, lk, facc);
                __syncthreads();
            }
            store_lds<4, 4, false>(R0, 512, wm * 64, wn * 64,
                b2 + li * 256 + wn * 64, lr, lk, facc);   // fs -> R0+R1 stride 512
        }
        __syncthreads();
        // ---- P12: x = LN(x + f) ----
        ln_rows(xs, R0, nullptr, 1, ln2g + li * 256, ln2b + li * 256, tid, nullptr);
        __syncthreads();
    }
    // ---- final LN -> out (f32) ----
    ln_rows(xs, nullptr, nullptr, 2, lnfg, lnfb, tid, out + (size_t)bc * 32768);
}

// ---------------------------------------------------------------------------
extern "C" void kernel_launch(void* const* d_in, const int* in_sizes, int n_in,
                              void* d_out, int out_size, void* d_ws, size_t ws_size,
                              hipStream_t stream)
{
    (void)in_sizes; (void)n_in; (void)out_size; (void)ws_size;
    const float* tgt   = (const float*)d_in[0];
    const float* Wlq   = (const float*)d_in[1];
    const float* Wlkv  = (const float*)d_in[2];
    const float* Wlp   = (const float*)d_in[3];
    const float* blp   = (const float*)d_in[4];
    const float* Whqkv = (const float*)d_in[5];
    const float* Whp   = (const float*)d_in[6];
    const float* bhp   = (const float*)d_in[7];
    const float* W1    = (const float*)d_in[8];
    const float* b1    = (const float*)d_in[9];
    const float* W2    = (const float*)d_in[10];
    const float* b2    = (const float*)d_in[11];
    const float* ln1g  = (const float*)d_in[12];
    const float* ln1b  = (const float*)d_in[13];
    const float* ln2g  = (const float*)d_in[14];
    const float* ln2b  = (const float*)d_in[15];
    const float* lnfg  = (const float*)d_in[16];
    const float* lnfb  = (const float*)d_in[17];

    unsigned short* wsu = (unsigned short*)d_ws;
    unsigned short* tWhqkv = wsu;             // 2*384*256 = 196608
    unsigned short* tWhp   = wsu + 196608;    // 2*128*128 =  32768
    unsigned short* tWlq   = wsu + 229376;    // 2*128*256 =  65536
    unsigned short* tWlkv  = wsu + 294912;    // 2*256*256 = 131072
    unsigned short* tWlp   = wsu + 425984;    // 2*128*128 =  32768
    unsigned short* tW1    = wsu + 458752;    // 2*512*256 = 262144
    unsigned short* tW2    = wsu + 720896;    // 2*256*512 = 262144

    wprep<<<dim3(8, 12, 2), 256, 0, stream>>>(Whqkv, tWhqkv, 256, 384);
    wprep<<<dim3(4,  4, 2), 256, 0, stream>>>(Whp,   tWhp,   128, 128);
    wprep<<<dim3(8,  4, 2), 256, 0, stream>>>(Wlq,   tWlq,   256, 128);
    wprep<<<dim3(8,  8, 2), 256, 0, stream>>>(Wlkv,  tWlkv,  256, 256);
    wprep<<<dim3(4,  4, 2), 256, 0, stream>>>(Wlp,   tWlp,   128, 128);
    wprep<<<dim3(8, 16, 2), 256, 0, stream>>>(W1,    tW1,    256, 512);
    wprep<<<dim3(16, 8, 2), 256, 0, stream>>>(W2,    tW2,    512, 256);

    hipFuncSetAttribute((const void*)enc_kernel,
                        hipFuncAttributeMaxDynamicSharedMemorySize, 163840);
    enc_kernel<<<1024, 512, 163840, stream>>>(
        tgt, tWhqkv, tWhp, tWlq, tWlkv, tWlp, tW1, tW2,
        bhp, blp, b1, b2, ln1g, ln1b, ln2g, ln2b, lnfg, lnfb, (float*)d_out);
}

// Round 3
// 2547.407 us; speedup vs baseline: 1.0897x; 1.0897x over previous
//
#include <hip/hip_runtime.h>
#include <hip/hip_bf16.h>

// ---------------------------------------------------------------------------
// WinEncoderTransformer mega-kernel: one block per batch element (bc),
// activations resident in LDS (bf16), weights pre-transposed to bf16 in d_ws.
// Geometry: N=128, B=1024, C=256; block bc owns flat rows [bc*128, bc*128+128).
// R2 fix: register-pressure. Round-1 spilled (VGPR capped 128 by
// __launch_bounds__(512,1) -> ~4 GB scratch traffic). Now: no min-wave clamp
// (8-wave block => 2 waves/SIMD => 256 VGPR budget) + chunked LDS dot/axpy in
// the scalar attention phases so peak live regs stay well under budget.
// ---------------------------------------------------------------------------

#define ATT_SCALE 0.17677669529663687f   // 32^-0.5

typedef float f32x4 __attribute__((ext_vector_type(4)));
typedef __bf16 bf16x8 __attribute__((ext_vector_type(8)));
typedef unsigned short u16x8 __attribute__((ext_vector_type(8)));
typedef unsigned short u16x4 __attribute__((ext_vector_type(4)));

__device__ __forceinline__ unsigned short f2bf(float f) {
    unsigned int u = __float_as_uint(f);
    return (unsigned short)((u + 0x7FFFu + ((u >> 16) & 1u)) >> 16);  // RNE
}
__device__ __forceinline__ float bf2f(unsigned short s) {
    return __uint_as_float(((unsigned int)s) << 16);
}

// ---------------------------------------------------------------------------
// weight prep: src [L][K][N] f32 -> dst [L][N][K] bf16 (transposed)
// ---------------------------------------------------------------------------
__global__ __launch_bounds__(256) void wprep(const float* __restrict__ src,
                                             unsigned short* __restrict__ dst,
                                             int K, int N)
{
    __shared__ unsigned short t[32][33];
    int l = blockIdx.z;
    const float* s = src + (size_t)l * K * N;
    unsigned short* d = dst + (size_t)l * K * N;
    int r = threadIdx.x >> 3, c4 = (threadIdx.x & 7) * 4;
    int kb = blockIdx.x * 32, nb = blockIdx.y * 32;
    f32x4 v = *(const f32x4*)(s + (size_t)(kb + r) * N + nb + c4);
    #pragma unroll
    for (int j = 0; j < 4; ++j) t[c4 + j][r] = f2bf(v[j]);
    __syncthreads();
    u16x4 o;
    #pragma unroll
    for (int j = 0; j < 4; ++j) o[j] = t[r][c4 + j];
    *(u16x4*)(d + (size_t)(nb + r) * K + kb + c4) = o;
}

// ---------------------------------------------------------------------------
// MFMA tile GEMM: A from swizzled LDS (bf16), B from global transposed bf16.
// LDS swizzle convention everywhere: byte = (row*stride + colbyte) ^ ((row&7)<<4)
// ---------------------------------------------------------------------------
template<int MT, int NT, int KS>
__device__ __forceinline__ void mfma_gemm(const char* As, int astride, int am0,
    const unsigned short* __restrict__ BT, int ldbk, int koff,
    int lr, int lk, f32x4 (&acc)[MT][NT])
{
    #pragma unroll
    for (int s = 0; s < KS; ++s) {
        bf16x8 bfr[NT];
        #pragma unroll
        for (int nt = 0; nt < NT; ++nt)
            bfr[nt] = *(const bf16x8*)(BT + (size_t)(nt * 16 + lr) * ldbk + koff + s * 32 + lk * 8);
        #pragma unroll
        for (int mt = 0; mt < MT; ++mt) {
            int row = am0 + mt * 16 + lr;
            bf16x8 afr = *(const bf16x8*)(As + ((row * astride + s * 64 + lk * 16) ^ ((row & 7) << 4)));
            #pragma unroll
            for (int nt = 0; nt < NT; ++nt)
                acc[mt][nt] = __builtin_amdgcn_mfma_f32_16x16x32_bf16(afr, bfr[nt], acc[mt][nt], 0, 0, 0);
        }
    }
}

template<int MT, int NT, bool RELU>
__device__ __forceinline__ void store_lds(char* Ds, int dstride, int dm0, int dn0,
    const float* bias, int lr, int lk, f32x4 (&acc)[MT][NT])
{
    #pragma unroll
    for (int nt = 0; nt < NT; ++nt) {
        float bv = bias ? bias[nt * 16 + lr] : 0.0f;
        #pragma unroll
        for (int mt = 0; mt < MT; ++mt) {
            #pragma unroll
            for (int j = 0; j < 4; ++j) {
                int row = dm0 + mt * 16 + lk * 4 + j;
                int col = dn0 + nt * 16 + lr;
                float v = acc[mt][nt][j] + bv;
                if (RELU) v = fmaxf(v, 0.0f);
                *(unsigned short*)(Ds + ((row * dstride + col * 2) ^ ((row & 7) << 4))) = f2bf(v);
            }
        }
    }
}

// read 32 consecutive bf16 (4 swizzled 16B chunks) as floats
__device__ __forceinline__ void lds_read32(const char* base, int stride, int row, int cb, float* o) {
    int x = row * stride, sw = (row & 7) << 4;
    #pragma unroll
    for (int c = 0; c < 4; ++c) {
        u16x8 t = *(const u16x8*)(base + ((x + cb + c * 16) ^ sw));
        #pragma unroll
        for (int j = 0; j < 8; ++j) o[c * 8 + j] = bf2f(t[j]);
    }
}
__device__ __forceinline__ void lds_write32(char* base, int stride, int row, int cb, const float* v) {
    int x = row * stride, sw = (row & 7) << 4;
    #pragma unroll
    for (int c = 0; c < 4; ++c) {
        u16x8 t;
        #pragma unroll
        for (int j = 0; j < 8; ++j) t[j] = f2bf(v[c * 8 + j]);
        *(u16x8*)(base + ((x + cb + c * 16) ^ sw)) = t;
    }
}
// fused dot: sum_i q[i] * lds_row[i] over 32 bf16 (8-elem transient)
__device__ __forceinline__ float lds_dot32(const char* base, int stride, int row, int cb, const float* q) {
    int x = row * stride, sw = (row & 7) << 4;
    float d = 0.0f;
    #pragma unroll
    for (int c = 0; c < 4; ++c) {
        u16x8 t = *(const u16x8*)(base + ((x + cb + c * 16) ^ sw));
        #pragma unroll
        for (int j = 0; j < 8; ++j) d += q[c * 8 + j] * bf2f(t[j]);
    }
    return d;
}
// fused axpy: o[i] += a * lds_row[i] over 32 bf16 (8-elem transient)
__device__ __forceinline__ void lds_axpy32(const char* base, int stride, int row, int cb, float a, float* o) {
    int x = row * stride, sw = (row & 7) << 4;
    #pragma unroll
    for (int c = 0; c < 4; ++c) {
        u16x8 t = *(const u16x8*)(base + ((x + cb + c * 16) ^ sw));
        #pragma unroll
        for (int j = 0; j < 8; ++j) o[c * 8 + j] += a * bf2f(t[j]);
    }
}

// ---------------------------------------------------------------------------
// LN over 256 cols. thread: row = tid>>2, quarter (tid&3)*64.
// mode 0: a = [hi(aHi,stride256) | lo(aLo,stride256)]; mode 1: a = aHi stride 512;
// mode 2: no residual. outp != null -> write f32 global, else write xs (bf16).
// ---------------------------------------------------------------------------
__device__ void ln_rows(char* xs, const char* aHi, const char* aLo, int mode,
                        const float* g, const float* b, int tid, float* outp)
{
    int row = tid >> 2, c0 = (tid & 3) * 64;
    float v[64];
    {
        int x = row * 512, sw = (row & 7) << 4;
        #pragma unroll
        for (int c = 0; c < 8; ++c) {
            u16x8 t = *(const u16x8*)(xs + ((x + c0 * 2 + c * 16) ^ sw));
            #pragma unroll
            for (int j = 0; j < 8; ++j) v[c * 8 + j] = bf2f(t[j]);
        }
    }
    if (mode == 0) {
        const char* ab = (c0 < 128) ? aHi : aLo;
        int cb = (c0 < 128) ? c0 * 2 : (c0 - 128) * 2;
        int x = row * 256, sw = (row & 7) << 4;
        #pragma unroll
        for (int c = 0; c < 8; ++c) {
            u16x8 t = *(const u16x8*)(ab + ((x + cb + c * 16) ^ sw));
            #pragma unroll
            for (int j = 0; j < 8; ++j) v[c * 8 + j] += bf2f(t[j]);
        }
    } else if (mode == 1) {
        int x = row * 512, sw = (row & 7) << 4;
        #pragma unroll
        for (int c = 0; c < 8; ++c) {
            u16x8 t = *(const u16x8*)(aHi + ((x + c0 * 2 + c * 16) ^ sw));
            #pragma unroll
            for (int j = 0; j < 8; ++j) v[c * 8 + j] += bf2f(t[j]);
        }
    }
    float s = 0.0f, sq = 0.0f;
    #pragma unroll
    for (int j = 0; j < 64; ++j) { s += v[j]; sq += v[j] * v[j]; }
    s += __shfl_xor(s, 1); s += __shfl_xor(s, 2);
    sq += __shfl_xor(sq, 1); sq += __shfl_xor(sq, 2);
    float mean = s * (1.0f / 256.0f);
    float var = sq * (1.0f / 256.0f) - mean * mean;
    float rstd = rsqrtf(var + 1e-5f);
    if (outp) {
        float* op = outp + (size_t)row * 256 + c0;
        #pragma unroll
        for (int c = 0; c < 16; ++c) {
            f32x4 gv = *(const f32x4*)(g + c0 + c * 4);
            f32x4 bv = *(const f32x4*)(b + c0 + c * 4);
            f32x4 ov;
            #pragma unroll
            for (int j = 0; j < 4; ++j) ov[j] = (v[c * 4 + j] - mean) * rstd * gv[j] + bv[j];
            *(f32x4*)(op + c * 4) = ov;
        }
    } else {
        int x = row * 512, sw = (row & 7) << 4;
        #pragma unroll
        for (int c = 0; c < 8; ++c) {
            u16x8 t;
            #pragma unroll
            for (int j = 0; j < 8; ++j) {
                float nv = (v[c * 8 + j] - mean) * rstd * g[c0 + c * 8 + j] + b[c0 + c * 8 + j];
                t[j] = f2bf(nv);
            }
            *(u16x8*)(xs + ((x + c0 * 2 + c * 16) ^ sw)) = t;
        }
    }
}

// ---------------------------------------------------------------------------
// The mega-kernel. 512 threads = 8 waves (2m x 4n for 128-row GEMMs).
// Dynamic LDS 160 KiB: xs[128][256]bf16 (64K) | sbuf 96K = R0|R1|R2 (32K each).
// ---------------------------------------------------------------------------
__global__ __launch_bounds__(512) void enc_kernel(
    const float* __restrict__ tgt,
    const unsigned short* __restrict__ tWhqkv,  // [L][384][256]
    const unsigned short* __restrict__ tWhp,    // [L][128][128]
    const unsigned short* __restrict__ tWlq,    // [L][128][256]
    const unsigned short* __restrict__ tWlkv,   // [L][256][256]
    const unsigned short* __restrict__ tWlp,    // [L][128][128]
    const unsigned short* __restrict__ tW1,     // [L][512][256]
    const unsigned short* __restrict__ tW2,     // [L][256][512]
    const float* __restrict__ bhp, const float* __restrict__ blp,
    const float* __restrict__ b1, const float* __restrict__ b2,
    const float* __restrict__ ln1g, const float* __restrict__ ln1b,
    const float* __restrict__ ln2g, const float* __restrict__ ln2b,
    const float* __restrict__ lnfg, const float* __restrict__ lnfb,
    float* __restrict__ out)
{
    extern __shared__ char smem[];
    char* xs = smem;              // [128] rows x 512 B (256 bf16), swizzled
    char* sb = smem + 65536;      // 96 KB scratch
    char* R0 = sb;
    char* R1 = sb + 32768;
    char* R2 = sb + 65536;

    const int tid = threadIdx.x;
    const int bc = blockIdx.x;
    const int w = tid >> 6, l = tid & 63;
    const int lr = l & 15, lk = l >> 4;
    const int wm = w >> 2, wn = w & 3;   // 2 x 4 wave grid

    // ---- load x tile: 128 rows x 256 f32 -> bf16 swizzled LDS ----
    {
        int row = tid >> 2, c0 = (tid & 3) * 64;
        const float* src = tgt + ((size_t)bc * 128 + row) * 256 + c0;
        int x = row * 512, sw = (row & 7) << 4;
        #pragma unroll
        for (int c = 0; c < 8; ++c) {
            f32x4 a = *(const f32x4*)(src + c * 8);
            f32x4 bq = *(const f32x4*)(src + c * 8 + 4);
            u16x8 t;
            #pragma unroll
            for (int j = 0; j < 4; ++j) { t[j] = f2bf(a[j]); t[4 + j] = f2bf(bq[j]); }
            *(u16x8*)(xs + ((x + c0 * 2 + c * 16) ^ sw)) = t;
        }
    }
    __syncthreads();

    for (int li = 0; li < 2; ++li) {
        // ---- P1: qkv = xs @ WhqkvT  (128x384, K=256) -> sb rows stride 768 ----
        {
            f32x4 acc[4][6] = {};
            mfma_gemm<4, 6, 8>(xs, 512, wm * 64,
                tWhqkv + (size_t)li * 98304 + (size_t)(wn * 96) * 256, 256, 0, lr, lk, acc);
            store_lds<4, 6, false>(sb, 768, wm * 64, wn * 96, nullptr, lr, lk, acc);
        }
        __syncthreads();
        // ---- P2: hifi windowed attention (thread = win,h,qi) ----
        {
            int win = tid >> 4, h = (tid >> 2) & 3, qi = tid & 3;
            int rbase = ((win >> 3) << 5) + ((win & 7) << 1);
            int qrow = rbase + ((qi >> 1) << 4) + (qi & 1);
            float q[32];
            lds_read32(sb, 768, qrow, h * 64, q);
            float s4[4];
            #pragma unroll
            for (int j = 0; j < 4; ++j) {
                int kr = rbase + ((j >> 1) << 4) + (j & 1);
                s4[j] = lds_dot32(sb, 768, kr, 256 + h * 64, q) * ATT_SCALE;
            }
            float mx = fmaxf(fmaxf(s4[0], s4[1]), fmaxf(s4[2], s4[3]));
            float den = 0.0f;
            #pragma unroll
            for (int j = 0; j < 4; ++j) { s4[j] = __expf(s4[j] - mx); den += s4[j]; }
            float inv = 1.0f / den;
            float o[32];
            #pragma unroll
            for (int i = 0; i < 32; ++i) o[i] = 0.0f;
            #pragma unroll
            for (int j = 0; j < 4; ++j) {
                int vr = rbase + ((j >> 1) << 4) + (j & 1);
                lds_axpy32(sb, 768, vr, 512 + h * 64, s4[j] * inv, o);
            }
            __syncthreads();                       // all qkv reads done
            lds_write32(R0, 256, qrow, h * 64, o); // os -> R0
        }
        __syncthreads();
        // ---- P3: hi = os @ WhpT + bhp -> R1 (as_hi) ----
        {
            f32x4 acc[4][2] = {};
            mfma_gemm<4, 2, 4>(R0, 256, wm * 64,
                tWhp + (size_t)li * 16384 + (size_t)(wn * 32) * 128, 128, 0, lr, lk, acc);
            store_lds<4, 2, false>(R1, 256, wm * 64, wn * 32,
                bhp + li * 128 + wn * 32, lr, lk, acc);
        }
        __syncthreads();
        // ---- P4: pool 2x2 windows -> xps R2[0:16K], [32][256] stride 512 ----
        {
            int p = tid >> 4, c16 = (tid & 15) * 16;
            int rb = ((p >> 3) << 5) + ((p & 7) << 1);
            int rows[4] = {rb, rb + 1, rb + 16, rb + 17};
            float a16[16] = {};
            #pragma unroll
            for (int rr = 0; rr < 4; ++rr) {
                int r = rows[rr];
                int x = r * 512, sw = (r & 7) << 4;
                #pragma unroll
                for (int c = 0; c < 2; ++c) {
                    u16x8 t = *(const u16x8*)(xs + ((x + c16 * 2 + c * 16) ^ sw));
                    #pragma unroll
                    for (int j = 0; j < 8; ++j) a16[c * 8 + j] += bf2f(t[j]);
                }
            }
            int x = p * 512, sw = (p & 7) << 4;
            #pragma unroll
            for (int c = 0; c < 2; ++c) {
                u16x8 t;
                #pragma unroll
                for (int j = 0; j < 8; ++j) t[j] = f2bf(a16[c * 8 + j] * 0.25f);
                *(u16x8*)(R2 + ((x + c16 * 2 + c * 16) ^ sw)) = t;
            }
        }
        __syncthreads();
        // ---- P5: kv = xps @ WlkvT (32x256) -> kvs R2+16K; P6: q = xs @ WlqT -> R0 ----
        {
            f32x4 acc[2][2] = {};
            mfma_gemm<2, 2, 8>(R2, 512, 0,
                tWlkv + (size_t)li * 65536 + (size_t)(w * 32) * 256, 256, 0, lr, lk, acc);
            store_lds<2, 2, false>(R2 + 16384, 512, 0, w * 32, nullptr, lr, lk, acc);
        }
        {
            f32x4 acc[4][2] = {};
            mfma_gemm<4, 2, 8>(xs, 512, wm * 64,
                tWlq + (size_t)li * 32768 + (size_t)(wn * 32) * 256, 256, 0, lr, lk, acc);
            store_lds<4, 2, false>(R0, 256, wm * 64, wn * 32, nullptr, lr, lk, acc);
        }
        __syncthreads();
        // ---- P7: lofi attention (thread = row,h): q(R0) vs kvs(R2+16K) ----
        {
            int row = tid >> 2, h = tid & 3;
            float q[32], sc[32];
            lds_read32(R0, 256, row, h * 64, q);
            #pragma unroll
            for (int p = 0; p < 32; ++p)
                sc[p] = lds_dot32(R2 + 16384, 512, p, h * 64, q) * ATT_SCALE;
            float mx = -1e30f;
            #pragma unroll
            for (int p = 0; p < 32; ++p) mx = fmaxf(mx, sc[p]);
            float den = 0.0f;
            #pragma unroll
            for (int p = 0; p < 32; ++p) { sc[p] = __expf(sc[p] - mx); den += sc[p]; }
            float inv = 1.0f / den;
            #pragma unroll
            for (int p = 0; p < 32; ++p) sc[p] *= inv;
            float o[32];                            // q dead here -> o reuses budget
            #pragma unroll
            for (int i = 0; i < 32; ++i) o[i] = 0.0f;
            #pragma unroll
            for (int p = 0; p < 32; ++p)
                lds_axpy32(R2 + 16384, 512, p, 256 + h * 64, sc[p], o);
            __syncthreads();                        // all q/kv reads done
            lds_write32(R2, 256, row, h * 64, o);   // los -> R2
        }
        __syncthreads();
        // ---- P8: lo = los @ WlpT + blp -> R0 (as_lo) ----
        {
            f32x4 acc[4][2] = {};
            mfma_gemm<4, 2, 4>(R2, 256, wm * 64,
                tWlp + (size_t)li * 16384 + (size_t)(wn * 32) * 128, 128, 0, lr, lk, acc);
            store_lds<4, 2, false>(R0, 256, wm * 64, wn * 32,
                blp + li * 128 + wn * 32, lr, lk, acc);
        }
        __syncthreads();
        // ---- P9: x = LN(x + [hi|lo]) ----
        ln_rows(xs, R1, R0, 0, ln1g + li * 256, ln1b + li * 256, tid, nullptr);
        __syncthreads();
        // ---- P10/P11: FFN with K-split, f accumulated in registers ----
        {
            f32x4 facc[4][4] = {};
            #pragma unroll
            for (int h = 0; h < 2; ++h) {
                f32x4 acch[4][4] = {};
                mfma_gemm<4, 4, 8>(xs, 512, wm * 64,
                    tW1 + (size_t)li * 131072 + (size_t)(h * 256 + wn * 64) * 256, 256, 0, lr, lk, acch);
                store_lds<4, 4, true>(R0, 512, wm * 64, wn * 64,
                    b1 + li * 512 + h * 256 + wn * 64, lr, lk, acch);
                __syncthreads();
                mfma_gemm<4, 4, 8>(R0, 512, wm * 64,
                    tW2 + (size_t)li * 131072 + (size_t)(wn * 64) * 512, 512, h * 256, lr, lk, facc);
                __syncthreads();
            }
            store_lds<4, 4, false>(R0, 512, wm * 64, wn * 64,
                b2 + li * 256 + wn * 64, lr, lk, facc);   // fs -> R0+R1 stride 512
        }
        __syncthreads();
        // ---- P12: x = LN(x + f) ----
        ln_rows(xs, R0, nullptr, 1, ln2g + li * 256, ln2b + li * 256, tid, nullptr);
        __syncthreads();
    }
    // ---- final LN -> out (f32) ----
    ln_rows(xs, nullptr, nullptr, 2, lnfg, lnfb, tid, out + (size_t)bc * 32768);
}

// ---------------------------------------------------------------------------
extern "C" void kernel_launch(void* const* d_in, const int* in_sizes, int n_in,
                              void* d_out, int out_size, void* d_ws, size_t ws_size,
                              hipStream_t stream)
{
    (void)in_sizes; (void)n_in; (void)out_size; (void)ws_size;
    const float* tgt   = (const float*)d_in[0];
    const float* Wlq   = (const float*)d_in[1];
    const float* Wlkv  = (const float*)d_in[2];
    const float* Wlp   = (const float*)d_in[3];
    const float* blp   = (const float*)d_in[4];
    const float* Whqkv = (const float*)d_in[5];
    const float* Whp   = (const float*)d_in[6];
    const float* bhp   = (const float*)d_in[7];
    const float* W1    = (const float*)d_in[8];
    const float* b1    = (const float*)d_in[9];
    const float* W2    = (const float*)d_in[10];
    const float* b2    = (const float*)d_in[11];
    const float* ln1g  = (const float*)d_in[12];
    const float* ln1b  = (const float*)d_in[13];
    const float* ln2g  = (const float*)d_in[14];
    const float* ln2b  = (const float*)d_in[15];
    const float* lnfg  = (const float*)d_in[16];
    const float* lnfb  = (const float*)d_in[17];

    unsigned short* wsu = (unsigned short*)d_ws;
    unsigned short* tWhqkv = wsu;             // 2*384*256 = 196608
    unsigned short* tWhp   = wsu + 196608;    // 2*128*128 =  32768
    unsigned short* tWlq   = wsu + 229376;    // 2*128*256 =  65536
    unsigned short* tWlkv  = wsu + 294912;    // 2*256*256 = 131072
    unsigned short* tWlp   = wsu + 425984;    // 2*128*128 =  32768
    unsigned short* tW1    = wsu + 458752;    // 2*512*256 = 262144
    unsigned short* tW2    = wsu + 720896;    // 2*256*512 = 262144

    wprep<<<dim3(8, 12, 2), 256, 0, stream>>>(Whqkv, tWhqkv, 256, 384);
    wprep<<<dim3(4,  4, 2), 256, 0, stream>>>(Whp,   tWhp,   128, 128);
    wprep<<<dim3(8,  4, 2), 256, 0, stream>>>(Wlq,   tWlq,   256, 128);
    wprep<<<dim3(8,  8, 2), 256, 0, stream>>>(Wlkv,  tWlkv,  256, 256);
    wprep<<<dim3(4,  4, 2), 256, 0, stream>>>(Wlp,   tWlp,   128, 128);
    wprep<<<dim3(8, 16, 2), 256, 0, stream>>>(W1,    tW1,    256, 512);
    wprep<<<dim3(16, 8, 2), 256, 0, stream>>>(W2,    tW2,    512, 256);

    hipFuncSetAttribute((const void*)enc_kernel,
                        hipFuncAttributeMaxDynamicSharedMemorySize, 163840);
    enc_kernel<<<1024, 512, 163840, stream>>>(
        tgt, tWhqkv, tWhp, tWlq, tWlkv, tWlp, tW1, tW2,
        bhp, blp, b1, b2, ln1g, ln1b, ln2g, ln2b, lnfg, lnfb, (float*)d_out);
}